// Round 6
// baseline (342.775 us; speedup 1.0000x reference)
//
#include <hip/hip_runtime.h>

constexpr int N = 50000;    // nodes
constexpr int E = 800000;   // edges
constexpr int NPAD = 50048; // padded to 64-row multiple for GEMM A tiles
constexpr int NB = (N + 255) / 256;   // 196 scan blocks

typedef _Float16 half8 __attribute__((ext_vector_type(8)));
typedef _Float16 half4v __attribute__((ext_vector_type(4)));
typedef float float4v __attribute__((ext_vector_type(4)));

// ---------------- degree / CSR ----------------
__global__ __launch_bounds__(256) void deg_kernel(const int* __restrict__ dst,
                                                  int* __restrict__ degI) {
    int e = blockIdx.x * 256 + threadIdx.x;
    if (e < E) atomicAdd(&degI[dst[e]], 1);
}

// ---- 3-phase scan (scan1 also emits dinv = rsqrt(deg+1)) ----
__global__ __launch_bounds__(256) void scan1_kernel(const int* __restrict__ degI,
                                                    int* __restrict__ incl,
                                                    int* __restrict__ blockSums,
                                                    float* __restrict__ dinv) {
    __shared__ int s[256];
    int t = threadIdx.x;
    int i = blockIdx.x * 256 + t;
    int d = (i < N) ? degI[i] : 0;
    if (i < N) dinv[i] = rsqrtf((float)d + 1.0f);   // +1 = self loop
    s[t] = d;
    __syncthreads();
    for (int off = 1; off < 256; off <<= 1) {
        int v = s[t];
        int u = (t >= off) ? s[t - off] : 0;
        __syncthreads();
        s[t] = v + u;
        __syncthreads();
    }
    if (i < N) incl[i] = s[t];
    if (t == 255) blockSums[blockIdx.x] = s[255];
}

__global__ __launch_bounds__(256) void scan2_kernel(int* __restrict__ blockSums) {
    __shared__ int s[256];
    int t = threadIdx.x;
    int v = (t < NB) ? blockSums[t] : 0;
    s[t] = v;
    __syncthreads();
    for (int off = 1; off < 256; off <<= 1) {
        int a = s[t];
        int u = (t >= off) ? s[t - off] : 0;
        __syncthreads();
        s[t] = a + u;
        __syncthreads();
    }
    if (t < NB) blockSums[t] = s[t] - v;   // exclusive block offset
}

__global__ __launch_bounds__(256) void scan3_kernel(const int* __restrict__ degI,
                                                    const int* __restrict__ incl,
                                                    const int* __restrict__ blockSums,
                                                    int* __restrict__ rowptr,
                                                    int* __restrict__ cursor) {
    int i = blockIdx.x * 256 + threadIdx.x;
    if (i < N) {
        int e = blockSums[blockIdx.x] + incl[i] - degI[i];
        rowptr[i] = e;
        cursor[i] = e;
    }
    if (i == 0) rowptr[N] = E;
}

__global__ __launch_bounds__(256) void fill_kernel(const int* __restrict__ src,
                                                   const int* __restrict__ dst,
                                                   int* __restrict__ cursor,
                                                   int* __restrict__ eidx) {
    int e = blockIdx.x * 256 + threadIdx.x;
    if (e >= E) return;
    int d = dst[e];
    int pos = atomicAdd(&cursor[d], 1);
    eidx[pos] = src[e];
}

// ---------------- both weight transposes in one kernel ----------------
// W1t[n][k] = (f16) W1[k][n]  (k<128, n<256);  W2t[n][k] = (f16) W2[k][n] (k<256)
__global__ __launch_bounds__(256) void wt_both_kernel(const float* __restrict__ W1,
                                                      const float* __restrict__ W2,
                                                      _Float16* __restrict__ W1t,
                                                      _Float16* __restrict__ W2t) {
    int idx = blockIdx.x * 256 + threadIdx.x;
    if (idx < 256 * 128) {
        int k = idx & 127;
        int n = idx >> 7;
        W1t[idx] = (_Float16)W1[(size_t)k * 256 + n];
    } else {
        int j = idx - 256 * 128;
        int k = j & 255;
        int n = j >> 8;
        W2t[j] = (_Float16)W2[(size_t)k * 256 + n];
    }
}

// ---------------- prescale: px = dinv[v] * x   (fp32 -> fp16, 128 ch) ----------------
__global__ __launch_bounds__(256) void prescale_kernel(const float4* __restrict__ x,
                                                       const float* __restrict__ dinv,
                                                       half4v* __restrict__ px) {
    int idx = blockIdx.x * 256 + threadIdx.x;
    if (idx >= N * 32) return;
    float dv = dinv[idx >> 5];
    float4 t = x[idx];
    half4v o;
    o[0] = (_Float16)(t.x * dv);
    o[1] = (_Float16)(t.y * dv);
    o[2] = (_Float16)(t.z * dv);
    o[3] = (_Float16)(t.w * dv);
    px[idx] = o;
}

// ---------------- fused aggregate + MFMA GEMM ----------------
// Phase A: aggregate 64 rows (q[v] = dinv[v]*(f[v] + sum_nbr f[u])) into an LDS
// A-tile (f16 -- same rounding as the old q round-trip => identical numerics).
// Gather: 16 B/lane half8, LPN=K/8 lanes per node, 8-edge unroll (R4 body --
// measured at the device random-gather line-rate ceiling ~55G lines/s).
// Phase B: 64x256 MFMA GEMM vs Wt, Bs staged 32 cols at a time (LDS <= 50.7 KB
// for K=256 -> 3 blocks/CU -> 384 gather-lines in flight/CU, above the rate
// knee per R4/R5 occupancy-insensitivity).
// FUSE1: out f16 = dinv[row]*relu(D+bias)  (becomes layer-2 gather table);
// else fp32 out = D+bias.
template <int K, bool FUSE1>
__global__ __launch_bounds__(256) void fused_agg_gemm(
    const int* __restrict__ rowptr, const int* __restrict__ eidx,
    const half8* __restrict__ f, const _Float16* __restrict__ Wt,
    const float* __restrict__ bias, const float* __restrict__ dinv,
    void* __restrict__ outp) {
    constexpr int LPN = K / 8;          // lanes per node (32 or 16)
    constexpr int NPB = 256 / LPN;      // nodes in flight (8 or 16)
    constexpr int LSTR = K + 8;         // halves; pad to spread LDS banks
    __shared__ _Float16 As[64 * LSTR];  // K=256: 33 KB, K=128: 17 KB
    __shared__ _Float16 Bs[32 * LSTR];  // K=256: 17 KB, K=128:  9 KB

    const int tid = threadIdx.x;
    const int rbase0 = blockIdx.x * 64;

    // ---------- phase A: aggregate 64 rows into As ----------
    {
        const int lane = tid % LPN;
        const int nsub = tid / LPN;
        for (int r = 0; r < 64; r += NPB) {
            const int row = r + nsub;
            const int v = rbase0 + row;
            float a[8] = {0.f, 0.f, 0.f, 0.f, 0.f, 0.f, 0.f, 0.f};
            if (v < N) {
                half8 s = f[(size_t)v * LPN + lane];
#pragma unroll
                for (int j = 0; j < 8; ++j) a[j] = (float)s[j];
                int i = rowptr[v];
                const int end = rowptr[v + 1];
                for (; i + 8 <= end; i += 8) {
                    int e0 = eidx[i + 0], e1 = eidx[i + 1];
                    int e2 = eidx[i + 2], e3 = eidx[i + 3];
                    int e4 = eidx[i + 4], e5 = eidx[i + 5];
                    int e6 = eidx[i + 6], e7 = eidx[i + 7];
                    half8 t0 = f[(size_t)e0 * LPN + lane];
                    half8 t1 = f[(size_t)e1 * LPN + lane];
                    half8 t2 = f[(size_t)e2 * LPN + lane];
                    half8 t3 = f[(size_t)e3 * LPN + lane];
                    half8 t4 = f[(size_t)e4 * LPN + lane];
                    half8 t5 = f[(size_t)e5 * LPN + lane];
                    half8 t6 = f[(size_t)e6 * LPN + lane];
                    half8 t7 = f[(size_t)e7 * LPN + lane];
#pragma unroll
                    for (int j = 0; j < 8; ++j) {
                        a[j] += (((float)t0[j] + (float)t1[j]) +
                                 ((float)t2[j] + (float)t3[j])) +
                                (((float)t4[j] + (float)t5[j]) +
                                 ((float)t6[j] + (float)t7[j]));
                    }
                }
                for (; i + 2 <= end; i += 2) {
                    int e0 = eidx[i], e1 = eidx[i + 1];
                    half8 t0 = f[(size_t)e0 * LPN + lane];
                    half8 t1 = f[(size_t)e1 * LPN + lane];
#pragma unroll
                    for (int j = 0; j < 8; ++j) a[j] += (float)t0[j] + (float)t1[j];
                }
                if (i < end) {
                    half8 t0 = f[(size_t)eidx[i] * LPN + lane];
#pragma unroll
                    for (int j = 0; j < 8; ++j) a[j] += (float)t0[j];
                }
                float dv = dinv[v];
#pragma unroll
                for (int j = 0; j < 8; ++j) a[j] *= dv;
            }
            half8 o;
#pragma unroll
            for (int j = 0; j < 8; ++j) o[j] = (_Float16)a[j];
            *(half8*)&As[row * LSTR + lane * 8] = o;
        }
    }
    __syncthreads();

    // ---------- phase B: (64 x K) @ (K x 256) MFMA GEMM ----------
    const int wave = tid >> 6;
    const int l64 = tid & 63;
    const int m = l64 & 15;
    const int quad = l64 >> 4;
    const int rbase = rbase0 + wave * 16;

    half8 af[K / 32];
#pragma unroll
    for (int i = 0; i < K / 32; ++i)
        af[i] = *(const half8*)&As[(wave * 16 + m) * LSTR + i * 32 + quad * 8];

    for (int cc = 0; cc < 8; ++cc) {
        const int colbase = cc * 32;
        if (cc) __syncthreads();
        // stage Wt rows [colbase, colbase+32) into Bs
        {
            int col = tid >> 3;
            int sub = tid & 7;
            const half8* srcb = (const half8*)(Wt + (size_t)(colbase + col) * K);
            half8* dstb = (half8*)&Bs[col * LSTR];
#pragma unroll
            for (int u = 0; u < K / 64; ++u) dstb[sub + u * 8] = srcb[sub + u * 8];
        }
        __syncthreads();

        float4v acc[2] = {};
#pragma unroll
        for (int k0 = 0; k0 < K; k0 += 32) {
            half8 a = af[k0 >> 5];
#pragma unroll
            for (int c = 0; c < 2; ++c) {
                half8 b = *(const half8*)&Bs[(c * 16 + m) * LSTR + k0 + quad * 8];
                acc[c] = __builtin_amdgcn_mfma_f32_16x16x32_f16(a, b, acc[c], 0, 0, 0);
            }
        }

#pragma unroll
        for (int c = 0; c < 2; ++c) {
            int col = colbase + c * 16 + m;
            float bcol = bias[col];
#pragma unroll
            for (int r = 0; r < 4; ++r) {
                int orow = rbase + quad * 4 + r;   // C/D: col=lane&15, row=quad*4+reg
                if (orow < N) {
                    float val = acc[c][r] + bcol;
                    if (FUSE1) {
                        val = fmaxf(val, 0.f) * dinv[orow];
                        ((_Float16*)outp)[(size_t)orow * 256 + col] = (_Float16)val;
                    } else {
                        ((float*)outp)[(size_t)orow * 256 + col] = val;
                    }
                }
            }
        }
    }
}

extern "C" void kernel_launch(void* const* d_in, const int* in_sizes, int n_in,
                              void* d_out, int out_size, void* d_ws, size_t ws_size,
                              hipStream_t stream) {
    const float* x  = (const float*)d_in[0];
    const int* edge = (const int*)d_in[1];
    const int* src  = edge;
    const int* dst  = edge + E;
    const float* W1 = (const float*)d_in[2];
    const float* b1 = (const float*)d_in[3];
    const float* W2 = (const float*)d_in[4];
    const float* b2 = (const float*)d_in[5];
    float* out = (float*)d_out;

    _Float16* bufA = (_Float16*)d_ws;
    _Float16* bufB = bufA + (size_t)NPAD * 256;
    float* dinv    = (float*)(bufB + (size_t)NPAD * 256);
    int* degI      = (int*)(dinv + N);
    int* rowptr    = degI + N;
    int* cursor    = rowptr + (N + 1);
    int* eidx      = cursor + N;
    _Float16* W1t  = (_Float16*)(eidx + E);
    _Float16* W2t  = W1t + 256 * 128;
    int* blockSums = (int*)(W2t + 256 * 256);

    // ---- CSR + normalization ----
    hipMemsetAsync(degI, 0, N * sizeof(int), stream);
    deg_kernel<<<(E + 255) / 256, 256, 0, stream>>>(dst, degI);
    scan1_kernel<<<NB, 256, 0, stream>>>(degI, cursor, blockSums, dinv);
    scan2_kernel<<<1, 256, 0, stream>>>(blockSums);
    scan3_kernel<<<NB, 256, 0, stream>>>(degI, cursor, blockSums, rowptr, cursor);
    fill_kernel<<<(E + 255) / 256, 256, 0, stream>>>(src, dst, cursor, eidx);

    // ---- weights to f16 transposed (both in one kernel) ----
    wt_both_kernel<<<(256 * 128 + 256 * 256) / 256, 256, 0, stream>>>(
        W1, W2, W1t, W2t);

    // ---- layer 1: h1p = dinv*relu((Ahat x)@W1 + b1), fused ----
    prescale_kernel<<<(N * 32 + 255) / 256, 256, 0, stream>>>(
        (const float4*)x, dinv, (half4v*)bufA);
    fused_agg_gemm<128, true><<<NPAD / 64, 256, 0, stream>>>(
        rowptr, eidx, (const half8*)bufA, W1t, b1, dinv, bufB);

    // ---- layer 2: out = (Ahat h1p)@W2 + b2, fused ----
    fused_agg_gemm<256, false><<<NPAD / 64, 256, 0, stream>>>(
        rowptr, eidx, (const half8*)bufB, W2t, b2, dinv, out);
}

// Round 8
// 330.248 us; speedup vs baseline: 1.0379x; 1.0379x over previous
//
#include <hip/hip_runtime.h>

constexpr int N = 50000;    // nodes
constexpr int E = 800000;   // edges
constexpr int NPAD = 50048; // padded to 128-row multiple for GEMM A tiles
constexpr int NB = (N + 255) / 256;   // 196 scan blocks
constexpr int DEG_BLKS = (E + 255) / 256;               // 3125
constexpr int WT_BLKS = (256 * 128 + 256 * 256) / 256;  // 384

typedef _Float16 half8 __attribute__((ext_vector_type(8)));
typedef _Float16 half4v __attribute__((ext_vector_type(4)));
typedef float float4v __attribute__((ext_vector_type(4)));

// ---------------- degree atomics + both weight transposes (one launch) --------
__global__ __launch_bounds__(256) void deg_wt_kernel(const int* __restrict__ dst,
                                                     int* __restrict__ degI,
                                                     const float* __restrict__ W1,
                                                     const float* __restrict__ W2,
                                                     _Float16* __restrict__ W1t,
                                                     _Float16* __restrict__ W2t) {
    int bid = blockIdx.x;
    int tid = threadIdx.x;
    if (bid < DEG_BLKS) {
        int e = bid * 256 + tid;
        if (e < E) atomicAdd(&degI[dst[e]], 1);
    } else {
        int idx = (bid - DEG_BLKS) * 256 + tid;
        if (idx < 256 * 128) {
            int k = idx & 127;
            int n = idx >> 7;
            W1t[idx] = (_Float16)W1[(size_t)k * 256 + n];
        } else {
            int j = idx - 256 * 128;
            int k = j & 255;
            int n = j >> 8;
            W2t[j] = (_Float16)W2[(size_t)k * 256 + n];
        }
    }
}

// ---- 3-phase scan (scan1 also emits dinv; scan3 also does prescale) ----
__global__ __launch_bounds__(256) void scan1_kernel(const int* __restrict__ degI,
                                                    int* __restrict__ incl,
                                                    int* __restrict__ blockSums,
                                                    float* __restrict__ dinv) {
    __shared__ int s[256];
    int t = threadIdx.x;
    int i = blockIdx.x * 256 + t;
    int d = (i < N) ? degI[i] : 0;
    if (i < N) dinv[i] = rsqrtf((float)d + 1.0f);   // +1 = self loop
    s[t] = d;
    __syncthreads();
    for (int off = 1; off < 256; off <<= 1) {
        int v = s[t];
        int u = (t >= off) ? s[t - off] : 0;
        __syncthreads();
        s[t] = v + u;
        __syncthreads();
    }
    if (i < N) incl[i] = s[t];
    if (t == 255) blockSums[blockIdx.x] = s[255];
}

__global__ __launch_bounds__(256) void scan2_kernel(int* __restrict__ blockSums) {
    __shared__ int s[256];
    int t = threadIdx.x;
    int v = (t < NB) ? blockSums[t] : 0;
    s[t] = v;
    __syncthreads();
    for (int off = 1; off < 256; off <<= 1) {
        int a = s[t];
        int u = (t >= off) ? s[t - off] : 0;
        __syncthreads();
        s[t] = a + u;
        __syncthreads();
    }
    if (t < NB) blockSums[t] = s[t] - v;   // exclusive block offset
}

__global__ __launch_bounds__(256) void scan3_kernel(const int* __restrict__ degI,
                                                    const int* __restrict__ incl,
                                                    const int* __restrict__ blockSums,
                                                    int* __restrict__ rowptr,
                                                    int* __restrict__ cursor,
                                                    const float* __restrict__ dinv,
                                                    const float4* __restrict__ x,
                                                    half4v* __restrict__ px) {
    int t = threadIdx.x;
    int bid = blockIdx.x;
    int i = bid * 256 + t;
    if (i < N) {
        int e = blockSums[bid] + incl[i] - degI[i];
        rowptr[i] = e;
        cursor[i] = e;
    }
    if (i == 0) rowptr[N] = E;

    // fused prescale: px = (f16)(dinv[v] * x), grid-stride, coalesced.
    // dinv was written by scan1 (previous launch) -> plain ordering, no barrier.
    for (int idx = bid * 256 + t; idx < N * 32; idx += NB * 256) {
        float dv = dinv[idx >> 5];
        float4 tt = x[idx];
        half4v o;
        o[0] = (_Float16)(tt.x * dv);
        o[1] = (_Float16)(tt.y * dv);
        o[2] = (_Float16)(tt.z * dv);
        o[3] = (_Float16)(tt.w * dv);
        px[idx] = o;
    }
}

__global__ __launch_bounds__(256) void fill_kernel(const int* __restrict__ src,
                                                   const int* __restrict__ dst,
                                                   int* __restrict__ cursor,
                                                   int* __restrict__ eidx) {
    int e = blockIdx.x * 256 + threadIdx.x;
    if (e >= E) return;
    int d = dst[e];
    int pos = atomicAdd(&cursor[d], 1);
    eidx[pos] = src[e];
}

// ---------------- gather-aggregate, 8-way MLP unroll (R0 proven body) ---------
template <int C4>
__global__ __launch_bounds__(256) void aggregate_f16(
    const int* __restrict__ rowptr, const int* __restrict__ eidx,
    const half4v* __restrict__ f, const float* __restrict__ dinv,
    half4v* __restrict__ q) {
    int v = blockIdx.x * (256 / C4) + threadIdx.x / C4;
    if (v >= N) return;
    int lane = threadIdx.x % C4;
    int beg = rowptr[v];
    int end = rowptr[v + 1];

    half4v sv = f[(size_t)v * C4 + lane];
    float a0 = (float)sv[0], a1 = (float)sv[1], a2 = (float)sv[2], a3 = (float)sv[3];

    int i = beg;
    for (; i + 8 <= end; i += 8) {
        int e0 = eidx[i + 0], e1 = eidx[i + 1], e2 = eidx[i + 2], e3 = eidx[i + 3];
        int e4 = eidx[i + 4], e5 = eidx[i + 5], e6 = eidx[i + 6], e7 = eidx[i + 7];
        half4v t0 = f[(size_t)e0 * C4 + lane];
        half4v t1 = f[(size_t)e1 * C4 + lane];
        half4v t2 = f[(size_t)e2 * C4 + lane];
        half4v t3 = f[(size_t)e3 * C4 + lane];
        half4v t4 = f[(size_t)e4 * C4 + lane];
        half4v t5 = f[(size_t)e5 * C4 + lane];
        half4v t6 = f[(size_t)e6 * C4 + lane];
        half4v t7 = f[(size_t)e7 * C4 + lane];
        a0 += ((float)t0[0] + (float)t1[0]) + ((float)t2[0] + (float)t3[0]) +
              ((float)t4[0] + (float)t5[0]) + ((float)t6[0] + (float)t7[0]);
        a1 += ((float)t0[1] + (float)t1[1]) + ((float)t2[1] + (float)t3[1]) +
              ((float)t4[1] + (float)t5[1]) + ((float)t6[1] + (float)t7[1]);
        a2 += ((float)t0[2] + (float)t1[2]) + ((float)t2[2] + (float)t3[2]) +
              ((float)t4[2] + (float)t5[2]) + ((float)t6[2] + (float)t7[2]);
        a3 += ((float)t0[3] + (float)t1[3]) + ((float)t2[3] + (float)t3[3]) +
              ((float)t4[3] + (float)t5[3]) + ((float)t6[3] + (float)t7[3]);
    }
    for (; i + 2 <= end; i += 2) {
        int e0 = eidx[i], e1 = eidx[i + 1];
        half4v t0 = f[(size_t)e0 * C4 + lane];
        half4v t1 = f[(size_t)e1 * C4 + lane];
        a0 += (float)t0[0] + (float)t1[0];
        a1 += (float)t0[1] + (float)t1[1];
        a2 += (float)t0[2] + (float)t1[2];
        a3 += (float)t0[3] + (float)t1[3];
    }
    if (i < end) {
        half4v t0 = f[(size_t)eidx[i] * C4 + lane];
        a0 += (float)t0[0];
        a1 += (float)t0[1];
        a2 += (float)t0[2];
        a3 += (float)t0[3];
    }

    float dv = dinv[v];
    half4v o;
    o[0] = (_Float16)(a0 * dv);
    o[1] = (_Float16)(a1 * dv);
    o[2] = (_Float16)(a2 * dv);
    o[3] = (_Float16)(a3 * dv);
    q[(size_t)v * C4 + lane] = o;
}

// ---------------- fp16 MFMA GEMM: 128 rows/block, Wt staged in LDS ------------
// Block: 128 rows x 256 cols. Each wave owns 32 rows as two 16-row tiles (rr),
// sharing the B-fragment between them (halves LDS reads per FLOP). Block count
// halves vs 64-row version -> total Wt staging traffic halves.
// FUSE1: f16 out = dinv*relu(D+bias); else fp32 out = D+bias.
template <int K, bool FUSE1>
__global__ __launch_bounds__(256) void gemm_mfma(
    const _Float16* __restrict__ A, const _Float16* __restrict__ Wt,
    const float* __restrict__ bias, const float* __restrict__ dinv,
    void* __restrict__ outp) {
    constexpr int LSTR = K + 8;                 // halves; pad to spread LDS banks
    __shared__ _Float16 Bs[64 * LSTR];          // K=256: 33 KB, K=128: 17 KB

    const int tid = threadIdx.x;
    const int wave = tid >> 6;
    const int lane = tid & 63;
    const int m = lane & 15;
    const int quad = lane >> 4;
    const int rbase = blockIdx.x * 128 + wave * 32;   // wave: rows [rbase, rbase+32)

    half8 af[2][K / 32];
#pragma unroll
    for (int rr = 0; rr < 2; ++rr) {
        const half8* Arow = (const half8*)(A + (size_t)(rbase + rr * 16 + m) * K);
#pragma unroll
        for (int i = 0; i < K / 32; ++i) af[rr][i] = Arow[i * 4 + quad];
    }

    for (int cc = 0; cc < 4; ++cc) {
        const int colbase = cc * 64;
        if (cc) __syncthreads();
        {
            int col = tid >> 2;
            int sub = tid & 3;
            const half8* srcb = (const half8*)(Wt + (size_t)(colbase + col) * K);
            half8* dstb = (half8*)&Bs[col * LSTR];
#pragma unroll
            for (int u = 0; u < K / 32; ++u) dstb[sub + u * 4] = srcb[sub + u * 4];
        }
        __syncthreads();

        float4v acc[2][4] = {};
#pragma unroll
        for (int k0 = 0; k0 < K; k0 += 32) {
            half8 a0 = af[0][k0 >> 5];
            half8 a1 = af[1][k0 >> 5];
#pragma unroll
            for (int c = 0; c < 4; ++c) {
                half8 b = *(const half8*)&Bs[(c * 16 + m) * LSTR + k0 + quad * 8];
                acc[0][c] = __builtin_amdgcn_mfma_f32_16x16x32_f16(a0, b, acc[0][c], 0, 0, 0);
                acc[1][c] = __builtin_amdgcn_mfma_f32_16x16x32_f16(a1, b, acc[1][c], 0, 0, 0);
            }
        }

#pragma unroll
        for (int c = 0; c < 4; ++c) {
            int col = colbase + c * 16 + m;
            float bcol = bias[col];
#pragma unroll
            for (int rr = 0; rr < 2; ++rr) {
#pragma unroll
                for (int r = 0; r < 4; ++r) {
                    int orow = rbase + rr * 16 + quad * 4 + r;
                    if (orow < N) {
                        float val = acc[rr][c][r] + bcol;
                        if (FUSE1) {
                            val = fmaxf(val, 0.f) * dinv[orow];
                            ((_Float16*)outp)[(size_t)orow * 256 + col] = (_Float16)val;
                        } else {
                            ((float*)outp)[(size_t)orow * 256 + col] = val;
                        }
                    }
                }
            }
        }
    }
}

extern "C" void kernel_launch(void* const* d_in, const int* in_sizes, int n_in,
                              void* d_out, int out_size, void* d_ws, size_t ws_size,
                              hipStream_t stream) {
    const float* x  = (const float*)d_in[0];
    const int* edge = (const int*)d_in[1];
    const int* src  = edge;
    const int* dst  = edge + E;
    const float* W1 = (const float*)d_in[2];
    const float* b1 = (const float*)d_in[3];
    const float* W2 = (const float*)d_in[4];
    const float* b2 = (const float*)d_in[5];
    float* out = (float*)d_out;

    _Float16* bufA = (_Float16*)d_ws;
    _Float16* bufB = bufA + (size_t)NPAD * 256;
    float* dinv    = (float*)(bufB + (size_t)NPAD * 256);
    int* degI      = (int*)(dinv + N);
    int* rowptr    = degI + N;
    int* cursor    = rowptr + (N + 1);
    int* eidx      = cursor + N;
    _Float16* W1t  = (_Float16*)(eidx + E);
    _Float16* W2t  = W1t + 256 * 128;
    int* blockSums = (int*)(W2t + 256 * 256);

    // ---- CSR + normalization + weights + prescale ----
    hipMemsetAsync(degI, 0, N * sizeof(int), stream);
    deg_wt_kernel<<<DEG_BLKS + WT_BLKS, 256, 0, stream>>>(
        dst, degI, W1, W2, W1t, W2t);
    scan1_kernel<<<NB, 256, 0, stream>>>(degI, cursor, blockSums, dinv);
    scan2_kernel<<<1, 256, 0, stream>>>(blockSums);
    scan3_kernel<<<NB, 256, 0, stream>>>(degI, cursor, blockSums, rowptr, cursor,
                                         dinv, (const float4*)x, (half4v*)bufA);
    fill_kernel<<<DEG_BLKS, 256, 0, stream>>>(src, dst, cursor, eidx);

    // ---- layer 1: h1p = dinv*relu((Ahat x)@W1 + b1) ----
    aggregate_f16<32><<<(N + 7) / 8, 256, 0, stream>>>(
        rowptr, eidx, (const half4v*)bufA, dinv, (half4v*)bufB);
    gemm_mfma<128, true><<<NPAD / 128, 256, 0, stream>>>(
        bufB, W1t, b1, dinv, bufA);

    // ---- layer 2: out = (Ahat h1p)@W2 + b2 ----
    aggregate_f16<64><<<(N + 3) / 4, 256, 0, stream>>>(
        rowptr, eidx, (const half4v*)bufA, dinv, (half4v*)bufB);
    gemm_mfma<256, false><<<NPAD / 128, 256, 0, stream>>>(
        bufB, W2t, b2, dinv, out);
}

// Round 9
// 315.685 us; speedup vs baseline: 1.0858x; 1.0461x over previous
//
#include <hip/hip_runtime.h>

constexpr int N = 50000;    // nodes
constexpr int E = 800000;   // edges
constexpr int NPAD = 50048; // padded to 64-row multiple for GEMM A tiles
constexpr int NB = (N + 255) / 256;   // 196 scan blocks

typedef _Float16 half8 __attribute__((ext_vector_type(8)));
typedef _Float16 half4v __attribute__((ext_vector_type(4)));
typedef float float4v __attribute__((ext_vector_type(4)));

// ---------------- degree / normalization / CSR ----------------
__global__ __launch_bounds__(256) void deg_kernel(const int* __restrict__ dst,
                                                  int* __restrict__ degI) {
    int e = blockIdx.x * 256 + threadIdx.x;
    if (e < E) atomicAdd(&degI[dst[e]], 1);
}

__global__ __launch_bounds__(256) void dinv_kernel(const int* __restrict__ degI,
                                                   float* __restrict__ dinv) {
    int v = blockIdx.x * 256 + threadIdx.x;
    if (v < N) dinv[v] = rsqrtf((float)degI[v] + 1.0f);   // +1 = self loop
}

// ---- 3-phase scan ----
__global__ __launch_bounds__(256) void scan1_kernel(const int* __restrict__ degI,
                                                    int* __restrict__ incl,
                                                    int* __restrict__ blockSums) {
    __shared__ int s[256];
    int t = threadIdx.x;
    int i = blockIdx.x * 256 + t;
    int d = (i < N) ? degI[i] : 0;
    s[t] = d;
    __syncthreads();
    for (int off = 1; off < 256; off <<= 1) {
        int v = s[t];
        int u = (t >= off) ? s[t - off] : 0;
        __syncthreads();
        s[t] = v + u;
        __syncthreads();
    }
    if (i < N) incl[i] = s[t];
    if (t == 255) blockSums[blockIdx.x] = s[255];
}

__global__ __launch_bounds__(256) void scan2_kernel(int* __restrict__ blockSums) {
    __shared__ int s[256];
    int t = threadIdx.x;
    int v = (t < NB) ? blockSums[t] : 0;
    s[t] = v;
    __syncthreads();
    for (int off = 1; off < 256; off <<= 1) {
        int a = s[t];
        int u = (t >= off) ? s[t - off] : 0;
        __syncthreads();
        s[t] = a + u;
        __syncthreads();
    }
    if (t < NB) blockSums[t] = s[t] - v;   // exclusive block offset
}

__global__ __launch_bounds__(256) void scan3_kernel(const int* __restrict__ degI,
                                                    const int* __restrict__ incl,
                                                    const int* __restrict__ blockSums,
                                                    int* __restrict__ rowptr,
                                                    int* __restrict__ cursor) {
    int i = blockIdx.x * 256 + threadIdx.x;
    if (i < N) {
        int e = blockSums[blockIdx.x] + incl[i] - degI[i];
        rowptr[i] = e;
        cursor[i] = e;
    }
    if (i == 0) rowptr[N] = E;
}

__global__ __launch_bounds__(256) void fill_kernel(const int* __restrict__ src,
                                                   const int* __restrict__ dst,
                                                   int* __restrict__ cursor,
                                                   int* __restrict__ eidx) {
    int e = blockIdx.x * 256 + threadIdx.x;
    if (e >= E) return;
    int d = dst[e];
    int pos = atomicAdd(&cursor[d], 1);
    eidx[pos] = src[e];
}

// ---------------- weight transpose+cast: Wt[n][k] = (f16) W[k][n] ----------------
template <int K>
__global__ __launch_bounds__(256) void wt_kernel(const float* __restrict__ W,
                                                 _Float16* __restrict__ Wt) {
    int idx = blockIdx.x * 256 + threadIdx.x;
    int k = idx & (K - 1);
    int n = idx >> (K == 128 ? 7 : 8);
    Wt[idx] = (_Float16)W[(size_t)k * 256 + n];
}

// ---------------- prescale: px = dinv[v] * x   (fp32 -> fp16, 128 ch) ----------------
__global__ __launch_bounds__(256) void prescale_kernel(const float4* __restrict__ x,
                                                       const float* __restrict__ dinv,
                                                       half4v* __restrict__ px) {
    int idx = blockIdx.x * 256 + threadIdx.x;
    if (idx >= N * 32) return;
    float dv = dinv[idx >> 5];
    float4 t = x[idx];
    half4v o;
    o[0] = (_Float16)(t.x * dv);
    o[1] = (_Float16)(t.y * dv);
    o[2] = (_Float16)(t.z * dv);
    o[3] = (_Float16)(t.w * dv);
    px[idx] = o;
}

// ---------------- gather-aggregate, 8-way MLP unroll (fp16 rows, fp32 accum) ------
template <int C4>
__global__ __launch_bounds__(256) void aggregate_f16(
    const int* __restrict__ rowptr, const int* __restrict__ eidx,
    const half4v* __restrict__ f, const float* __restrict__ dinv,
    half4v* __restrict__ q) {
    int v = blockIdx.x * (256 / C4) + threadIdx.x / C4;
    if (v >= N) return;
    int lane = threadIdx.x % C4;
    int beg = rowptr[v];
    int end = rowptr[v + 1];

    half4v sv = f[(size_t)v * C4 + lane];
    float a0 = (float)sv[0], a1 = (float)sv[1], a2 = (float)sv[2], a3 = (float)sv[3];

    int i = beg;
    for (; i + 8 <= end; i += 8) {
        int e0 = eidx[i + 0], e1 = eidx[i + 1], e2 = eidx[i + 2], e3 = eidx[i + 3];
        int e4 = eidx[i + 4], e5 = eidx[i + 5], e6 = eidx[i + 6], e7 = eidx[i + 7];
        half4v t0 = f[(size_t)e0 * C4 + lane];
        half4v t1 = f[(size_t)e1 * C4 + lane];
        half4v t2 = f[(size_t)e2 * C4 + lane];
        half4v t3 = f[(size_t)e3 * C4 + lane];
        half4v t4 = f[(size_t)e4 * C4 + lane];
        half4v t5 = f[(size_t)e5 * C4 + lane];
        half4v t6 = f[(size_t)e6 * C4 + lane];
        half4v t7 = f[(size_t)e7 * C4 + lane];
        a0 += ((float)t0[0] + (float)t1[0]) + ((float)t2[0] + (float)t3[0]) +
              ((float)t4[0] + (float)t5[0]) + ((float)t6[0] + (float)t7[0]);
        a1 += ((float)t0[1] + (float)t1[1]) + ((float)t2[1] + (float)t3[1]) +
              ((float)t4[1] + (float)t5[1]) + ((float)t6[1] + (float)t7[1]);
        a2 += ((float)t0[2] + (float)t1[2]) + ((float)t2[2] + (float)t3[2]) +
              ((float)t4[2] + (float)t5[2]) + ((float)t6[2] + (float)t7[2]);
        a3 += ((float)t0[3] + (float)t1[3]) + ((float)t2[3] + (float)t3[3]) +
              ((float)t4[3] + (float)t5[3]) + ((float)t6[3] + (float)t7[3]);
    }
    for (; i + 2 <= end; i += 2) {
        int e0 = eidx[i], e1 = eidx[i + 1];
        half4v t0 = f[(size_t)e0 * C4 + lane];
        half4v t1 = f[(size_t)e1 * C4 + lane];
        a0 += (float)t0[0] + (float)t1[0];
        a1 += (float)t0[1] + (float)t1[1];
        a2 += (float)t0[2] + (float)t1[2];
        a3 += (float)t0[3] + (float)t1[3];
    }
    if (i < end) {
        half4v t0 = f[(size_t)eidx[i] * C4 + lane];
        a0 += (float)t0[0];
        a1 += (float)t0[1];
        a2 += (float)t0[2];
        a3 += (float)t0[3];
    }

    float dv = dinv[v];
    half4v o;
    o[0] = (_Float16)(a0 * dv);
    o[1] = (_Float16)(a1 * dv);
    o[2] = (_Float16)(a2 * dv);
    o[3] = (_Float16)(a3 * dv);
    q[(size_t)v * C4 + lane] = o;
}

// ---------------- fp16 MFMA GEMM: A-frags in regs, Wt staged in LDS ----------------
// Block: 64 rows x 256 cols (4 col-chunks of 64). A row-major [NPAD,K] f16,
// Wt row-major [256,K] f16. A is read exactly once per block (all K in regs).
// FUSE1: out f16 = dinv[row]*relu(D+bias); else fp32 out = D+bias.
template <int K, bool FUSE1>
__global__ __launch_bounds__(256) void gemm_mfma(
    const _Float16* __restrict__ A, const _Float16* __restrict__ Wt,
    const float* __restrict__ bias, const float* __restrict__ dinv,
    void* __restrict__ outp) {
    constexpr int LSTR = K + 8;                 // halves; pad to spread LDS banks
    __shared__ _Float16 Bs[64 * LSTR];          // K=256: 33 KB, K=128: 17 KB

    const int tid = threadIdx.x;
    const int wave = tid >> 6;
    const int lane = tid & 63;
    const int m = lane & 15;
    const int quad = lane >> 4;
    const int rbase = blockIdx.x * 64 + wave * 16;
    const int row = rbase + m;

    // All A-fragments for this lane's row, whole K: independent global loads.
    half8 af[K / 32];
    {
        const half8* Arow = (const half8*)(A + (size_t)row * K);
#pragma unroll
        for (int i = 0; i < K / 32; ++i) af[i] = Arow[i * 4 + quad];
    }

    for (int cc = 0; cc < 4; ++cc) {
        const int colbase = cc * 64;
        if (cc) __syncthreads();
        // stage Wt rows [colbase, colbase+64) into LDS (16 B per thread per unit)
        {
            int col = tid >> 2;
            int sub = tid & 3;
            const half8* srcb = (const half8*)(Wt + (size_t)(colbase + col) * K);
            half8* dstb = (half8*)&Bs[col * LSTR];
#pragma unroll
            for (int u = 0; u < K / 32; ++u) dstb[sub + u * 4] = srcb[sub + u * 4];
        }
        __syncthreads();

        float4v acc[4] = {};
#pragma unroll
        for (int k0 = 0; k0 < K; k0 += 32) {
            half8 a = af[k0 >> 5];
#pragma unroll
            for (int c = 0; c < 4; ++c) {
                half8 b = *(const half8*)&Bs[(c * 16 + m) * LSTR + k0 + quad * 8];
                acc[c] = __builtin_amdgcn_mfma_f32_16x16x32_f16(a, b, acc[c], 0, 0, 0);
            }
        }

#pragma unroll
        for (int c = 0; c < 4; ++c) {
            int col = colbase + c * 16 + m;
            float bcol = bias[col];
#pragma unroll
            for (int r = 0; r < 4; ++r) {
                int orow = rbase + quad * 4 + r;   // C/D: col=lane&15, row=quad*4+reg
                if (orow < N) {
                    float val = acc[c][r] + bcol;
                    if (FUSE1) {
                        val = fmaxf(val, 0.f) * dinv[orow];
                        ((_Float16*)outp)[(size_t)orow * 256 + col] = (_Float16)val;
                    } else {
                        ((float*)outp)[(size_t)orow * 256 + col] = val;
                    }
                }
            }
        }
    }
}

extern "C" void kernel_launch(void* const* d_in, const int* in_sizes, int n_in,
                              void* d_out, int out_size, void* d_ws, size_t ws_size,
                              hipStream_t stream) {
    const float* x  = (const float*)d_in[0];
    const int* edge = (const int*)d_in[1];
    const int* src  = edge;
    const int* dst  = edge + E;
    const float* W1 = (const float*)d_in[2];
    const float* b1 = (const float*)d_in[3];
    const float* W2 = (const float*)d_in[4];
    const float* b2 = (const float*)d_in[5];
    float* out = (float*)d_out;

    _Float16* bufA = (_Float16*)d_ws;
    _Float16* bufB = bufA + (size_t)NPAD * 256;
    float* dinv    = (float*)(bufB + (size_t)NPAD * 256);
    int* degI      = (int*)(dinv + N);
    int* rowptr    = degI + N;
    int* cursor    = rowptr + (N + 1);
    int* eidx      = cursor + N;
    _Float16* W1t  = (_Float16*)(eidx + E);
    _Float16* W2t  = W1t + 256 * 128;
    int* blockSums = (int*)(W2t + 256 * 256);

    // ---- CSR + normalization ----
    hipMemsetAsync(degI, 0, N * sizeof(int), stream);
    deg_kernel<<<(E + 255) / 256, 256, 0, stream>>>(dst, degI);
    dinv_kernel<<<(N + 255) / 256, 256, 0, stream>>>(degI, dinv);
    scan1_kernel<<<NB, 256, 0, stream>>>(degI, cursor, blockSums);
    scan2_kernel<<<1, 256, 0, stream>>>(blockSums);
    scan3_kernel<<<NB, 256, 0, stream>>>(degI, cursor, blockSums, rowptr, cursor);
    fill_kernel<<<(E + 255) / 256, 256, 0, stream>>>(src, dst, cursor, eidx);

    // ---- weights to f16 transposed ----
    wt_kernel<128><<<(256 * 128) / 256, 256, 0, stream>>>(W1, W1t);
    wt_kernel<256><<<(256 * 256) / 256, 256, 0, stream>>>(W2, W2t);

    // ---- layer 1:  q1 = Ahat x (aggregate first), h1p = dinv*relu(q1@W1+b1) ----
    prescale_kernel<<<(N * 32 + 255) / 256, 256, 0, stream>>>(
        (const float4*)x, dinv, (half4v*)bufA);
    aggregate_f16<32><<<(N + 7) / 8, 256, 0, stream>>>(
        rowptr, eidx, (const half4v*)bufA, dinv, (half4v*)bufB);
    gemm_mfma<128, true><<<NPAD / 64, 256, 0, stream>>>(
        bufB, W1t, b1, dinv, bufA);

    // ---- layer 2:  q2 = Ahat h1, out = q2@W2 + b2 ----
    aggregate_f16<64><<<(N + 3) / 4, 256, 0, stream>>>(
        rowptr, eidx, (const half4v*)bufA, dinv, (half4v*)bufB);
    gemm_mfma<256, false><<<NPAD / 64, 256, 0, stream>>>(
        bufB, W2t, b2, dinv, out);
}